// Round 17
// baseline (60.841 us; speedup 1.0000x reference)
//
#include <hip/hip_runtime.h>

typedef unsigned long long u64;
typedef unsigned int u32;

#define NBOX 8192
#define NW64 128    // u64 words per fallback suppression bitmap
#define NCLASS 80
#define NCMAX 256   // fast-path class size cap; overflow flags exact fallback
#define CHKCAP 256
#define NS 32       // rank slices
#define SLICE 256   // NBOX / NS
#define NBLK 32     // i-range blocks (decode / scatter)
#define IPT 8       // i's per thread in rank blocks
#define RGROUPS 4   // 8192 / (256*IPT)
#define RANKB (NS * RGROUPS)         // 128 rank blocks
#define K2GRID (NCLASS + 1 + RANKB)  // class(0..79) + hazard(80) + rank(81..208)
#define K3GRID (NBLK + 1)            // scatter + fallback
#define SMEMSZ 15616

// ---- monotone float<->uint mapping (order-preserving for all floats) ----
__device__ __forceinline__ u32 f32_mono(float f) {
  u32 u = __float_as_uint(f);
  return (u & 0x80000000u) ? ~u : (u | 0x80000000u);
}
__device__ __forceinline__ float mono_f32(u32 u) {
  u32 b = (u & 0x80000000u) ? (u ^ 0x80000000u) : ~u;
  return __uint_as_float(b);
}
__device__ __forceinline__ u64 readlane64(u64 v, int l) {
  u32 lo = __builtin_amdgcn_readlane((u32)v, l);
  u32 hi = __builtin_amdgcn_readlane((u32)(v >> 32), l);
  return ((u64)hi << 32) | (u64)lo;
}
__device__ __forceinline__ u32 reduce_bmax(const u32* __restrict__ bmax, int t) {
  u32 bm = bmax[t & 31];
#pragma unroll
  for (int off = 16; off > 0; off >>= 1) {
    u32 o = __shfl_xor(bm, off);
    bm = (bm > o) ? bm : o;
  }
  return bm;
}

// NOTES (measured lessons):
// r7/r8: in-kernel grid barriers dead on gfx950 (~20-27us each). Plain nodes.
// r11: mask-then-scan beats the serial-IoU chain. r12/r14/r15: node count
//   ~1us each; per-block work deltas don't move the total; boundaries cheap.
// r16 accounting: every counter low + short blocks + cheap boundaries ->
//   hypothesis: WORKGROUP DISPATCH RATE (~25-30ns/WG x ~1170 WGs) is the
//   floor. This round: 1024 rank WGs -> 128 (8 i's/thread share each LDS
//   read); total WGs 1170 -> 402. Neutral result refutes the theory.

// ---- K1: decode -> boxes_out, bmax[32], per-block class-hist partials ----
__global__ __launch_bounds__(256) void decode_kernel(
    const float4* __restrict__ deltas, const float2* __restrict__ locs,
    const int* __restrict__ stride_p, const int* __restrict__ class_ids,
    float4* __restrict__ boxes_out, u32* __restrict__ bmax,
    int* __restrict__ ccpart) {
  const int t = threadIdx.x;
  const int i = blockIdx.x * 256 + t;
  __shared__ u32 wmax[4];
  __shared__ int lhist[NCLASS];
  if (t < NCLASS) lhist[t] = 0;
  float s = (float)(*stride_p);
  float4 d = deltas[i];
  d.x = fmaxf(d.x, 0.f); d.y = fmaxf(d.y, 0.f);
  d.z = fmaxf(d.z, 0.f); d.w = fmaxf(d.w, 0.f);
  float2 c = locs[i];
  float4 bb;
  bb.x = c.x - s * d.x;
  bb.y = c.y - s * d.y;
  bb.z = c.x + s * d.z;
  bb.w = c.y + s * d.w;
  boxes_out[i] = bb;
  float m = fmaxf(fmaxf(bb.x, bb.y), fmaxf(bb.z, bb.w));
  u32 u = f32_mono(m);
#pragma unroll
  for (int off = 32; off > 0; off >>= 1) {
    u32 o = __shfl_xor(u, off);
    u = (u > o) ? u : o;
  }
  if ((t & 63) == 0) wmax[t >> 6] = u;
  __syncthreads();  // lhist init + wmax ready
  atomicAdd(&lhist[class_ids[i]], 1);
  if (t == 0) {
    u32 m0 = wmax[0] > wmax[1] ? wmax[0] : wmax[1];
    u32 m1 = wmax[2] > wmax[3] ? wmax[2] : wmax[3];
    bmax[blockIdx.x] = m0 > m1 ? m0 : m1;
  }
  __syncthreads();
  if (t < NCLASS) ccpart[blockIdx.x * NCLASS + t] = lhist[t];  // plain store
}

// ---- K2: [0..79] class-NMS; [80] lean hazard -> flag; [81..208] rank ----
__global__ __launch_bounds__(256) void rank_nms_kernel(
    const float* __restrict__ scores, const int* __restrict__ class_ids,
    const float4* __restrict__ boxes, const u32* __restrict__ bmax,
    const int* __restrict__ ccpart, float* __restrict__ keep_out,
    int* __restrict__ flag, int* __restrict__ rankp) {
  const int t = threadIdx.x;
  const int bid = blockIdx.x;
  __shared__ __align__(16) char smem[SMEMSZ];  // union across roles

  if (bid < NCLASS) {
    // ---- class block: gather -> local rank -> mask -> bitmask scan ----
    const int c = bid;
    u64* ck = (u64*)smem;                        // 2048 B
    u32* slist = (u32*)(smem + 2048);            // 1024 B
    float4* bx = (float4*)(smem + 3072);         // 4096 B
    u64(*smask)[4] = (u64(*)[4])(smem + 7168);   // 8192 B
    int* cnt_s = (int*)(smem + 15360);
    if (t == 0) *cnt_s = 0;
    __syncthreads();

    float M = mono_f32(reduce_bmax(bmax, t));
    float off = (float)c * (M + 1.0f);

    {  // vectorized gather: 8 int4/float4 iterations, all loads in flight
      const int4* ci4 = (const int4*)class_ids;
      const float4* sc4 = (const float4*)scores;
#pragma unroll
      for (int it = 0; it < 8; ++it) {
        int g = it * 256 + t;
        int4 c4 = ci4[g];
        float4 s4 = sc4[g];
        int e = g * 4;
        if (c4.x == c) { int p = atomicAdd(cnt_s, 1); if (p < NCMAX) ck[p] = ((u64)(~f32_mono(s4.x)) << 32) | (u32)(e); }
        if (c4.y == c) { int p = atomicAdd(cnt_s, 1); if (p < NCMAX) ck[p] = ((u64)(~f32_mono(s4.y)) << 32) | (u32)(e + 1); }
        if (c4.z == c) { int p = atomicAdd(cnt_s, 1); if (p < NCMAX) ck[p] = ((u64)(~f32_mono(s4.z)) << 32) | (u32)(e + 2); }
        if (c4.w == c) { int p = atomicAdd(cnt_s, 1); if (p < NCMAX) ck[p] = ((u64)(~f32_mono(s4.w)) << 32) | (u32)(e + 3); }
      }
    }
    __syncthreads();
    int nc = *cnt_s;
    if (nc > NCMAX) return;  // hazard's ccpart check flags -> K3 fallback

    // local stable rank: ascending (~mono(score), idx) == (score desc, idx)
    if (t < nc) {
      u64 kme = ck[t];
      int r2 = 0;
      for (int p = 0; p < nc; ++p) r2 += (ck[p] < kme) ? 1 : 0;
      slist[r2] = (u32)kme;
    }
    __syncthreads();

    for (int k = t; k < nc; k += 256) {
      float4 bb = boxes[slist[k]];
      bb.x += off; bb.y += off; bb.z += off; bb.w += off;
      bx[k] = bb;
    }
    __syncthreads();

    {  // parallel mask: row i by wave (i&3); one ballot per 64-j word
      const int wv = t >> 6;
      const int lane = t & 63;
      const int nw = (nc + 63) >> 6;
      for (int i = wv; i < nc; i += 4) {
        float4 bi = bx[i];
        float area_i = (bi.z - bi.x) * (bi.w - bi.y);
        for (int w = 0; w < nw; ++w) {
          int j2 = w * 64 + lane;
          float4 bj = bx[j2 < NCMAX ? j2 : 0];
          float ltx = fmaxf(bi.x, bj.x), lty = fmaxf(bi.y, bj.y);
          float rbx = fminf(bi.z, bj.z), rby = fminf(bi.w, bj.w);
          float ww = fmaxf(rbx - ltx, 0.f), hh = fmaxf(rby - lty, 0.f);
          float inter = ww * hh;
          float area_j = (bj.z - bj.x) * (bj.w - bj.y);
          float iou = inter / (area_i + area_j - inter);
          bool p = (iou > 0.5f) && (j2 > i) && (j2 < nc);
          u64 mm = __ballot(p);
          if (lane == 0) smask[i][w] = mm;
        }
      }
    }
    __syncthreads();
    if (t >= 64) return;

    // wave 0: bitmask-only greedy scan (no IoU in the serial chain)
    u64 ma[4], mb[4], mc[4], md[4];
#pragma unroll
    for (int w = 0; w < 4; ++w) {
      ma[w] = smask[t][w];
      mb[w] = smask[64 + t][w];
      mc[w] = smask[128 + t][w];
      md[w] = smask[192 + t][w];
    }
    u64 R0 = 0, R1 = 0, R2 = 0, R3 = 0;
    u64 K0 = 0, K1 = 0, K2 = 0, K3 = 0;

#define SCAND(D, MD, RD, KD)                                                   \
  {                                                                            \
    int lim = nc - (D) * 64;                                                   \
    if (lim > 0) {                                                             \
      if (lim > 64) lim = 64;                                                  \
      for (int ii = 0; ii < lim; ++ii) {                                       \
        u64 kb = ((RD >> ii) & 1ull) ^ 1ull;                                   \
        KD |= kb << ii;                                                        \
        u64 sm2 = 0ull - kb;                                                   \
        R0 |= readlane64(MD[0], ii) & sm2;                                     \
        R1 |= readlane64(MD[1], ii) & sm2;                                     \
        R2 |= readlane64(MD[2], ii) & sm2;                                     \
        R3 |= readlane64(MD[3], ii) & sm2;                                     \
      }                                                                        \
    }                                                                          \
  }
    SCAND(0, ma, R0, K0)
    SCAND(1, mb, R1, K1)
    SCAND(2, mc, R2, K2)
    SCAND(3, md, R3, K3)
#undef SCAND

    u64 kk[4] = {K0, K1, K2, K3};
#pragma unroll
    for (int d = 0; d < 4; ++d) {
      int j = d * 64 + t;
      if (j < nc) keep_out[slist[j]] = ((kk[d] >> t) & 1ull) ? 1.0f : 0.0f;
    }
    return;
  }

  if (bid == NCLASS) {
    // ---- lean hazard block (sole flag writer).
    // (a) class overflow via ccpart column sums; (b) geometric margin scan:
    // adjacent-class offset boxes can only overlap if one hugs the top-right
    // margin (x2,y2 > M-65; x1,y1 >= -64 by construction) and the other the
    // bottom-left (x1,y1 < 1); conservative IoU > 0.4 vs reference 0.5.
    float4* bxA = (float4*)smem;                  // 4096 B
    float4* bxB = (float4*)(smem + 4096);         // 4096 B
    int* clsA = (int*)(smem + 8192);              // 1024 B
    int* clsB = (int*)(smem + 9216);              // 1024 B
    int* cnts = (int*)(smem + 10240);             // na, nb, hitf
    if (t == 0) { cnts[0] = 0; cnts[1] = 0; cnts[2] = 0; }
    __syncthreads();
    if (t < NCLASS) {
      int ssum = 0;
#pragma unroll 8
      for (int b2 = 0; b2 < NBLK; ++b2) ssum += ccpart[b2 * NCLASS + t];
      if (ssum > NCMAX) atomicOr(&cnts[2], 1);
    }
    float M = mono_f32(reduce_bmax(bmax, t));
    float thrA = M - 65.0f;
#pragma unroll
    for (int it = 0; it < 4; ++it) {  // 8 independent loads per batch
      float4 v[8];
      int cl[8];
#pragma unroll
      for (int r = 0; r < 8; ++r) v[r] = boxes[it * 2048 + r * 256 + t];
#pragma unroll
      for (int r = 0; r < 8; ++r) cl[r] = class_ids[it * 2048 + r * 256 + t];
#pragma unroll
      for (int r = 0; r < 8; ++r) {
        if (v[r].z > thrA && v[r].w > thrA) {
          int p = atomicAdd(&cnts[0], 1);
          if (p < CHKCAP) { bxA[p] = v[r]; clsA[p] = cl[r]; }
        }
        if (v[r].x < 1.0f && v[r].y < 1.0f) {
          int p = atomicAdd(&cnts[1], 1);
          if (p < CHKCAP) { bxB[p] = v[r]; clsB[p] = cl[r]; }
        }
      }
    }
    __syncthreads();
    int na = cnts[0], nb = cnts[1];
    int NA = na < CHKCAP ? na : CHKCAP;
    int NB = nb < CHKCAP ? nb : CHKCAP;
    bool hit = (t == 0) && (na > CHKCAP || nb > CHKCAP);
    for (int pr = t; pr < NA * NB; pr += 256) {
      int a = pr / NB, b2 = pr % NB;
      if (clsB[b2] != clsA[a] + 1) continue;
      float offa = (float)clsA[a] * (M + 1.0f);
      float offb = (float)clsB[b2] * (M + 1.0f);
      float4 A = bxA[a], Bb = bxB[b2];
      A.x += offa; A.y += offa; A.z += offa; A.w += offa;
      Bb.x += offb; Bb.y += offb; Bb.z += offb; Bb.w += offb;
      float ltx = fmaxf(A.x, Bb.x), lty = fmaxf(A.y, Bb.y);
      float rbx = fminf(A.z, Bb.z), rby = fminf(A.w, Bb.w);
      float ww = fmaxf(rbx - ltx, 0.f), hh = fmaxf(rby - lty, 0.f);
      float inter = ww * hh;
      float aa = (A.z - A.x) * (A.w - A.y);
      float ab = (Bb.z - Bb.x) * (Bb.w - Bb.y);
      float iou = inter / (aa + ab - inter);
      if (iou > 0.4f) hit = true;
    }
    if (hit) atomicOr(&cnts[2], 1);
    __syncthreads();
    if (t == 0) *flag = cnts[2];  // plain store; clears stale value per replay
    return;
  }

  // ---- rank blocks: 8 i's per thread share each LDS score read ----
  // rank = #{s_j > s_i} + #{s_j == s_i && j < i}
  const int rb = bid - (NCLASS + 1);  // 0..127
  const int slice = rb >> 2;          // 0..31
  const int g = rb & 3;               // i-group (2048 i's each)
  u32* st = (u32*)smem;
  st[t] = f32_mono(scores[slice * 256 + t]);
  __syncthreads();
  const int ibase = g * 2048 + t;
  u32 mi[IPT];
  int cnt[IPT];
#pragma unroll
  for (int k = 0; k < IPT; ++k) {
    mi[k] = f32_mono(scores[ibase + k * 256]);
    cnt[k] = 0;
  }
  const int sbase = slice * 256;
#pragma unroll 4
  for (int p = 0; p < SLICE; ++p) {
    u32 mj = st[p];  // uniform LDS address -> broadcast, shared by 8 i's
    int jj = sbase + p;
#pragma unroll
    for (int k = 0; k < IPT; ++k) {
      int ii = ibase + k * 256;
      bool less = (mj > mi[k]) || (mj == mi[k] && jj < ii);
      cnt[k] += less ? 1 : 0;
    }
  }
#pragma unroll
  for (int k = 0; k < IPT; ++k)
    rankp[slice * NBOX + ibase + k * 256] = cnt[k];
}

// ---- K3: scatter (blocks 0..31: order_out) + exact fallback (block 32,
// flag != 0 only; self-contained — perm from rankp, boxes from boxes_out).
__global__ __launch_bounds__(256) void scatter_fallback_kernel(
    const int* __restrict__ class_ids, const float4* __restrict__ boxes,
    const u32* __restrict__ bmax, const int* __restrict__ rankp,
    float* __restrict__ order_out, float* __restrict__ keep_out,
    const int* __restrict__ flag) {
  const int t = threadIdx.x;
  const int bid = blockIdx.x;

  if (bid < NBLK) {  // ---- scatter: order output ----
    int i = bid * 256 + t;
    int r = 0;
#pragma unroll
    for (int s2 = 0; s2 < NS; ++s2) r += rankp[s2 * NBOX + i];
    order_out[r] = (float)i;
    return;
  }

  // ---- block 32: exact fallback ----
  if (*flag == 0) return;
  __shared__ u32 perm[NBOX];  // 32 KiB
  __shared__ u64 remv[NW64];
  for (int k = t; k < NW64; k += 256) remv[k] = 0;
  for (int i = t; i < NBOX; i += 256) {
    int r = 0;
#pragma unroll
    for (int s2 = 0; s2 < NS; ++s2) r += rankp[s2 * NBOX + i];
    perm[r] = (u32)i;
  }
  __syncthreads();
  float maxc = mono_f32(reduce_bmax(bmax, t));
  if (t < 64) {
    int lane = t;
    for (int ii = 0; ii < NBOX; ++ii) {
      if ((remv[ii >> 6] >> (ii & 63)) & 1ull) continue;
      u32 pi = perm[ii];
      float offi = (float)class_ids[pi] * (maxc + 1.0f);
      float4 bi = boxes[pi];
      bi.x += offi; bi.y += offi; bi.z += offi; bi.w += offi;
      float area_i = (bi.z - bi.x) * (bi.w - bi.y);
      for (int jb = ii + 1; jb < NBOX; jb += 64) {
        int j = jb + lane;
        bool p = false;
        if (j < NBOX) {
          u32 pj = perm[j];
          float offj = (float)class_ids[pj] * (maxc + 1.0f);
          float4 bj = boxes[pj];
          bj.x += offj; bj.y += offj; bj.z += offj; bj.w += offj;
          float ltx = fmaxf(bi.x, bj.x), lty = fmaxf(bi.y, bj.y);
          float rbx = fminf(bi.z, bj.z), rby = fminf(bi.w, bj.w);
          float ww = fmaxf(rbx - ltx, 0.f), hh = fmaxf(rby - lty, 0.f);
          float inter = ww * hh;
          float area_j = (bj.z - bj.x) * (bj.w - bj.y);
          float iou = inter / (area_i + area_j - inter);
          p = iou > 0.5f;
        }
        u64 m = __ballot(p);
        if (lane == 0 && m) {
          int w0 = jb >> 6, sh = jb & 63;
          remv[w0] |= (m << sh);
          if (sh && (w0 + 1) < NW64) remv[w0 + 1] |= (m >> (64 - sh));
        }
      }
    }
  }
  __syncthreads();
  for (int k = t; k < NBOX; k += 256)
    keep_out[perm[k]] = ((remv[k >> 6] >> (k & 63)) & 1ull) ? 0.0f : 1.0f;
}

extern "C" void kernel_launch(void* const* d_in, const int* in_sizes, int n_in,
                              void* d_out, int out_size, void* d_ws, size_t ws_size,
                              hipStream_t stream) {
  const float* deltas = (const float*)d_in[0];
  const float* locs = (const float*)d_in[1];
  const float* scores = (const float*)d_in[2];
  const int* class_ids = (const int*)d_in[3];
  const int* stride_p = (const int*)d_in[4];

  float* boxes_out = (float*)d_out;                     // n*4 floats
  float* keep_out = (float*)d_out + (size_t)NBOX * 4;   // n floats (0/1)
  float* order_out = (float*)d_out + (size_t)NBOX * 5;  // n floats (indices)

  // workspace layout (all init in-kernel; no memset nodes)
  u32* bmax = (u32*)((char*)d_ws + 64);       // 32*4 B, stored by K1
  int* flag = (int*)((char*)d_ws + 256);      // stored by K2 hazard block
  int* ccpart = (int*)((char*)d_ws + 512);    // 32*80*4 B, stored by K1
  int* rankp = (int*)((char*)d_ws + 16384);   // NS*8192*4 = 1 MiB

  decode_kernel<<<NBLK, 256, 0, stream>>>(
      (const float4*)deltas, (const float2*)locs, stride_p, class_ids,
      (float4*)boxes_out, bmax, ccpart);

  rank_nms_kernel<<<K2GRID, 256, 0, stream>>>(
      scores, class_ids, (const float4*)boxes_out, bmax, ccpart, keep_out,
      flag, rankp);

  scatter_fallback_kernel<<<K3GRID, 256, 0, stream>>>(
      class_ids, (const float4*)boxes_out, bmax, rankp, order_out, keep_out,
      flag);
}

// Round 18
// 42.097 us; speedup vs baseline: 1.4453x; 1.4453x over previous
//
#include <hip/hip_runtime.h>

typedef unsigned long long u64;
typedef unsigned int u32;

#define NBOX 8192
#define NW64 128    // u64 words per fallback suppression bitmap
#define NCLASS 80
#define NCMAX 256   // fast-path class size cap; overflow flags exact fallback
#define CHKCAP 256
#define NS 32       // rank slices
#define SLICE 256   // NBOX / NS
#define NBLK 32     // i-range blocks
#define RANKB (NS * NBLK)            // 1024
#define K2GRID (NCLASS + 1 + RANKB)  // class(0..79) + hazard(80) + rank(81..)
#define K3GRID (NBLK + 1)            // scatter + fallback
#define SMEMSZ 15616

// ---- monotone float<->uint mapping (order-preserving for all floats) ----
__device__ __forceinline__ u32 f32_mono(float f) {
  u32 u = __float_as_uint(f);
  return (u & 0x80000000u) ? ~u : (u | 0x80000000u);
}
__device__ __forceinline__ float mono_f32(u32 u) {
  u32 b = (u & 0x80000000u) ? (u ^ 0x80000000u) : ~u;
  return __uint_as_float(b);
}
__device__ __forceinline__ u64 readlane64(u64 v, int l) {
  u32 lo = __builtin_amdgcn_readlane((u32)v, l);
  u32 hi = __builtin_amdgcn_readlane((u32)(v >> 32), l);
  return ((u64)hi << 32) | (u64)lo;
}
__device__ __forceinline__ u32 reduce_bmax(const u32* __restrict__ bmax, int t) {
  u32 bm = bmax[t & 31];
#pragma unroll
  for (int off = 16; off > 0; off >>= 1) {
    u32 o = __shfl_xor(bm, off);
    bm = (bm > o) ? bm : o;
  }
  return bm;
}

// NOTES (measured lessons):
// r7/r8: in-kernel grid barriers dead on gfx950 (~20-27us each). Plain nodes.
// r11: mask-then-scan beats the serial-IoU chain. r12: node count ~1us each.
// r13/r15/r17: clist-precompute, preamble-removal, and WG-count-reduction all
//   FAILED to beat r16 — bottom-up cycle estimates are uniformly ~5x under
//   measured durations while memory-bound fills hit 86% HBM peak: consistent
//   with a shader-clock DVFS floor on tiny low-util kernels. Under that model
//   the winning config is max phase overlap + thin parallel blocks = r16.
// This round: exact revert to r16 (best measured, 42.6us).

// ---- K1: decode -> boxes_out, bmax[32], per-block class-hist partials ----
__global__ __launch_bounds__(256) void decode_kernel(
    const float4* __restrict__ deltas, const float2* __restrict__ locs,
    const int* __restrict__ stride_p, const int* __restrict__ class_ids,
    float4* __restrict__ boxes_out, u32* __restrict__ bmax,
    int* __restrict__ ccpart) {
  const int t = threadIdx.x;
  const int i = blockIdx.x * 256 + t;
  __shared__ u32 wmax[4];
  __shared__ int lhist[NCLASS];
  if (t < NCLASS) lhist[t] = 0;
  float s = (float)(*stride_p);
  float4 d = deltas[i];
  d.x = fmaxf(d.x, 0.f); d.y = fmaxf(d.y, 0.f);
  d.z = fmaxf(d.z, 0.f); d.w = fmaxf(d.w, 0.f);
  float2 c = locs[i];
  float4 bb;
  bb.x = c.x - s * d.x;
  bb.y = c.y - s * d.y;
  bb.z = c.x + s * d.z;
  bb.w = c.y + s * d.w;
  boxes_out[i] = bb;
  float m = fmaxf(fmaxf(bb.x, bb.y), fmaxf(bb.z, bb.w));
  u32 u = f32_mono(m);
#pragma unroll
  for (int off = 32; off > 0; off >>= 1) {
    u32 o = __shfl_xor(u, off);
    u = (u > o) ? u : o;
  }
  if ((t & 63) == 0) wmax[t >> 6] = u;
  __syncthreads();  // lhist init + wmax ready
  atomicAdd(&lhist[class_ids[i]], 1);
  if (t == 0) {
    u32 m0 = wmax[0] > wmax[1] ? wmax[0] : wmax[1];
    u32 m1 = wmax[2] > wmax[3] ? wmax[2] : wmax[3];
    bmax[blockIdx.x] = m0 > m1 ? m0 : m1;
  }
  __syncthreads();
  if (t < NCLASS) ccpart[blockIdx.x * NCLASS + t] = lhist[t];  // plain store
}

// ---- K2: [0..79] class-NMS (first -> CU slots at t=0, overlap rank)
//          [80] lean hazard (ccpart overflow + batched margin scan) -> flag
//          [81..1104] u32 score-rank partials
__global__ __launch_bounds__(256) void rank_nms_kernel(
    const float* __restrict__ scores, const int* __restrict__ class_ids,
    const float4* __restrict__ boxes, const u32* __restrict__ bmax,
    const int* __restrict__ ccpart, float* __restrict__ keep_out,
    int* __restrict__ flag, int* __restrict__ rankp) {
  const int t = threadIdx.x;
  const int bid = blockIdx.x;
  __shared__ __align__(16) char smem[SMEMSZ];  // union across roles

  if (bid < NCLASS) {
    // ---- class block: gather -> local rank -> mask -> bitmask scan ----
    const int c = bid;
    u64* ck = (u64*)smem;                        // 2048 B
    u32* slist = (u32*)(smem + 2048);            // 1024 B
    float4* bx = (float4*)(smem + 3072);         // 4096 B
    u64(*smask)[4] = (u64(*)[4])(smem + 7168);   // 8192 B
    int* cnt_s = (int*)(smem + 15360);
    if (t == 0) *cnt_s = 0;
    __syncthreads();

    float M = mono_f32(reduce_bmax(bmax, t));
    float off = (float)c * (M + 1.0f);

    {  // vectorized gather: 8 int4/float4 iterations, all loads in flight
      const int4* ci4 = (const int4*)class_ids;
      const float4* sc4 = (const float4*)scores;
#pragma unroll
      for (int it = 0; it < 8; ++it) {
        int g = it * 256 + t;
        int4 c4 = ci4[g];
        float4 s4 = sc4[g];
        int e = g * 4;
        if (c4.x == c) { int p = atomicAdd(cnt_s, 1); if (p < NCMAX) ck[p] = ((u64)(~f32_mono(s4.x)) << 32) | (u32)(e); }
        if (c4.y == c) { int p = atomicAdd(cnt_s, 1); if (p < NCMAX) ck[p] = ((u64)(~f32_mono(s4.y)) << 32) | (u32)(e + 1); }
        if (c4.z == c) { int p = atomicAdd(cnt_s, 1); if (p < NCMAX) ck[p] = ((u64)(~f32_mono(s4.z)) << 32) | (u32)(e + 2); }
        if (c4.w == c) { int p = atomicAdd(cnt_s, 1); if (p < NCMAX) ck[p] = ((u64)(~f32_mono(s4.w)) << 32) | (u32)(e + 3); }
      }
    }
    __syncthreads();
    int nc = *cnt_s;
    if (nc > NCMAX) return;  // hazard's ccpart check flags -> K3 fallback

    // local stable rank: ascending (~mono(score), idx) == (score desc, idx)
    if (t < nc) {
      u64 kme = ck[t];
      int r2 = 0;
      for (int p = 0; p < nc; ++p) r2 += (ck[p] < kme) ? 1 : 0;
      slist[r2] = (u32)kme;
    }
    __syncthreads();

    for (int k = t; k < nc; k += 256) {
      float4 bb = boxes[slist[k]];
      bb.x += off; bb.y += off; bb.z += off; bb.w += off;
      bx[k] = bb;
    }
    __syncthreads();

    {  // parallel mask: row i by wave (i&3); one ballot per 64-j word
      const int wv = t >> 6;
      const int lane = t & 63;
      const int nw = (nc + 63) >> 6;
      for (int i = wv; i < nc; i += 4) {
        float4 bi = bx[i];
        float area_i = (bi.z - bi.x) * (bi.w - bi.y);
        for (int w = 0; w < nw; ++w) {
          int j2 = w * 64 + lane;
          float4 bj = bx[j2 < NCMAX ? j2 : 0];
          float ltx = fmaxf(bi.x, bj.x), lty = fmaxf(bi.y, bj.y);
          float rbx = fminf(bi.z, bj.z), rby = fminf(bi.w, bj.w);
          float ww = fmaxf(rbx - ltx, 0.f), hh = fmaxf(rby - lty, 0.f);
          float inter = ww * hh;
          float area_j = (bj.z - bj.x) * (bj.w - bj.y);
          float iou = inter / (area_i + area_j - inter);
          bool p = (iou > 0.5f) && (j2 > i) && (j2 < nc);
          u64 mm = __ballot(p);
          if (lane == 0) smask[i][w] = mm;
        }
      }
    }
    __syncthreads();
    if (t >= 64) return;

    // wave 0: bitmask-only greedy scan (no IoU in the serial chain)
    u64 ma[4], mb[4], mc[4], md[4];
#pragma unroll
    for (int w = 0; w < 4; ++w) {
      ma[w] = smask[t][w];
      mb[w] = smask[64 + t][w];
      mc[w] = smask[128 + t][w];
      md[w] = smask[192 + t][w];
    }
    u64 R0 = 0, R1 = 0, R2 = 0, R3 = 0;
    u64 K0 = 0, K1 = 0, K2 = 0, K3 = 0;

#define SCAND(D, MD, RD, KD)                                                   \
  {                                                                            \
    int lim = nc - (D) * 64;                                                   \
    if (lim > 0) {                                                             \
      if (lim > 64) lim = 64;                                                  \
      for (int ii = 0; ii < lim; ++ii) {                                       \
        u64 kb = ((RD >> ii) & 1ull) ^ 1ull;                                   \
        KD |= kb << ii;                                                        \
        u64 sm2 = 0ull - kb;                                                   \
        R0 |= readlane64(MD[0], ii) & sm2;                                     \
        R1 |= readlane64(MD[1], ii) & sm2;                                     \
        R2 |= readlane64(MD[2], ii) & sm2;                                     \
        R3 |= readlane64(MD[3], ii) & sm2;                                     \
      }                                                                        \
    }                                                                          \
  }
    SCAND(0, ma, R0, K0)
    SCAND(1, mb, R1, K1)
    SCAND(2, mc, R2, K2)
    SCAND(3, md, R3, K3)
#undef SCAND

    u64 kk[4] = {K0, K1, K2, K3};
#pragma unroll
    for (int d = 0; d < 4; ++d) {
      int j = d * 64 + t;
      if (j < nc) keep_out[slist[j]] = ((kk[d] >> t) & 1ull) ? 1.0f : 0.0f;
    }
    return;
  }

  if (bid == NCLASS) {
    // ---- lean hazard block (sole flag writer).
    // (a) class overflow via ccpart column sums; (b) geometric margin scan:
    // adjacent-class offset boxes can only overlap if one hugs the top-right
    // margin (x2,y2 > M-65; x1,y1 >= -64 by construction) and the other the
    // bottom-left (x1,y1 < 1); conservative IoU > 0.4 vs reference 0.5.
    float4* bxA = (float4*)smem;                  // 4096 B
    float4* bxB = (float4*)(smem + 4096);         // 4096 B
    int* clsA = (int*)(smem + 8192);              // 1024 B
    int* clsB = (int*)(smem + 9216);              // 1024 B
    int* cnts = (int*)(smem + 10240);             // na, nb, hitf
    if (t == 0) { cnts[0] = 0; cnts[1] = 0; cnts[2] = 0; }
    __syncthreads();
    if (t < NCLASS) {
      int ssum = 0;
#pragma unroll 8
      for (int b2 = 0; b2 < NBLK; ++b2) ssum += ccpart[b2 * NCLASS + t];
      if (ssum > NCMAX) atomicOr(&cnts[2], 1);
    }
    float M = mono_f32(reduce_bmax(bmax, t));
    float thrA = M - 65.0f;
#pragma unroll
    for (int it = 0; it < 4; ++it) {  // 8 independent loads per batch
      float4 v[8];
      int cl[8];
#pragma unroll
      for (int r = 0; r < 8; ++r) v[r] = boxes[it * 2048 + r * 256 + t];
#pragma unroll
      for (int r = 0; r < 8; ++r) cl[r] = class_ids[it * 2048 + r * 256 + t];
#pragma unroll
      for (int r = 0; r < 8; ++r) {
        if (v[r].z > thrA && v[r].w > thrA) {
          int p = atomicAdd(&cnts[0], 1);
          if (p < CHKCAP) { bxA[p] = v[r]; clsA[p] = cl[r]; }
        }
        if (v[r].x < 1.0f && v[r].y < 1.0f) {
          int p = atomicAdd(&cnts[1], 1);
          if (p < CHKCAP) { bxB[p] = v[r]; clsB[p] = cl[r]; }
        }
      }
    }
    __syncthreads();
    int na = cnts[0], nb = cnts[1];
    int NA = na < CHKCAP ? na : CHKCAP;
    int NB = nb < CHKCAP ? nb : CHKCAP;
    bool hit = (t == 0) && (na > CHKCAP || nb > CHKCAP);
    for (int pr = t; pr < NA * NB; pr += 256) {
      int a = pr / NB, b2 = pr % NB;
      if (clsB[b2] != clsA[a] + 1) continue;
      float offa = (float)clsA[a] * (M + 1.0f);
      float offb = (float)clsB[b2] * (M + 1.0f);
      float4 A = bxA[a], Bb = bxB[b2];
      A.x += offa; A.y += offa; A.z += offa; A.w += offa;
      Bb.x += offb; Bb.y += offb; Bb.z += offb; Bb.w += offb;
      float ltx = fmaxf(A.x, Bb.x), lty = fmaxf(A.y, Bb.y);
      float rbx = fminf(A.z, Bb.z), rby = fminf(A.w, Bb.w);
      float ww = fmaxf(rbx - ltx, 0.f), hh = fmaxf(rby - lty, 0.f);
      float inter = ww * hh;
      float aa = (A.z - A.x) * (A.w - A.y);
      float ab = (Bb.z - Bb.x) * (Bb.w - Bb.y);
      float iou = inter / (aa + ab - inter);
      if (iou > 0.4f) hit = true;
    }
    if (hit) atomicOr(&cnts[2], 1);
    __syncthreads();
    if (t == 0) *flag = cnts[2];  // plain store; clears stale value per replay
    return;
  }

  // ---- rank blocks: rank = #{s_j > s_i} + #{s_j == s_i && j < i} ----
  const int rb = bid - (NCLASS + 1);
  const int bi = rb & 31;
  const int slice = rb >> 5;
  const int i = bi * 256 + t;
  u32* st = (u32*)smem;
  st[t] = f32_mono(scores[slice * 256 + t]);
  __syncthreads();
  u32 mi = f32_mono(scores[i]);
  int tp = i - slice * 256;  // j<i <=> p<tp
  int cnt = 0;
#pragma unroll 8
  for (int p = 0; p < SLICE; ++p) {
    u32 mj = st[p];  // uniform LDS address -> broadcast
    bool less = (mj > mi) || (mj == mi && p < tp);
    cnt += less ? 1 : 0;
  }
  rankp[slice * NBOX + i] = cnt;
}

// ---- K3: scatter (blocks 0..31: order_out) + exact fallback (block 32,
// flag != 0 only; self-contained — perm from rankp, boxes from boxes_out).
__global__ __launch_bounds__(256) void scatter_fallback_kernel(
    const int* __restrict__ class_ids, const float4* __restrict__ boxes,
    const u32* __restrict__ bmax, const int* __restrict__ rankp,
    float* __restrict__ order_out, float* __restrict__ keep_out,
    const int* __restrict__ flag) {
  const int t = threadIdx.x;
  const int bid = blockIdx.x;

  if (bid < NBLK) {  // ---- scatter: order output ----
    int i = bid * 256 + t;
    int r = 0;
#pragma unroll
    for (int s2 = 0; s2 < NS; ++s2) r += rankp[s2 * NBOX + i];
    order_out[r] = (float)i;
    return;
  }

  // ---- block 32: exact fallback ----
  if (*flag == 0) return;
  __shared__ u32 perm[NBOX];  // 32 KiB
  __shared__ u64 remv[NW64];
  for (int k = t; k < NW64; k += 256) remv[k] = 0;
  for (int i = t; i < NBOX; i += 256) {
    int r = 0;
#pragma unroll
    for (int s2 = 0; s2 < NS; ++s2) r += rankp[s2 * NBOX + i];
    perm[r] = (u32)i;
  }
  __syncthreads();
  float maxc = mono_f32(reduce_bmax(bmax, t));
  if (t < 64) {
    int lane = t;
    for (int ii = 0; ii < NBOX; ++ii) {
      if ((remv[ii >> 6] >> (ii & 63)) & 1ull) continue;
      u32 pi = perm[ii];
      float offi = (float)class_ids[pi] * (maxc + 1.0f);
      float4 bi = boxes[pi];
      bi.x += offi; bi.y += offi; bi.z += offi; bi.w += offi;
      float area_i = (bi.z - bi.x) * (bi.w - bi.y);
      for (int jb = ii + 1; jb < NBOX; jb += 64) {
        int j = jb + lane;
        bool p = false;
        if (j < NBOX) {
          u32 pj = perm[j];
          float offj = (float)class_ids[pj] * (maxc + 1.0f);
          float4 bj = boxes[pj];
          bj.x += offj; bj.y += offj; bj.z += offj; bj.w += offj;
          float ltx = fmaxf(bi.x, bj.x), lty = fmaxf(bi.y, bj.y);
          float rbx = fminf(bi.z, bj.z), rby = fminf(bi.w, bj.w);
          float ww = fmaxf(rbx - ltx, 0.f), hh = fmaxf(rby - lty, 0.f);
          float inter = ww * hh;
          float area_j = (bj.z - bj.x) * (bj.w - bj.y);
          float iou = inter / (area_i + area_j - inter);
          p = iou > 0.5f;
        }
        u64 m = __ballot(p);
        if (lane == 0 && m) {
          int w0 = jb >> 6, sh = jb & 63;
          remv[w0] |= (m << sh);
          if (sh && (w0 + 1) < NW64) remv[w0 + 1] |= (m >> (64 - sh));
        }
      }
    }
  }
  __syncthreads();
  for (int k = t; k < NBOX; k += 256)
    keep_out[perm[k]] = ((remv[k >> 6] >> (k & 63)) & 1ull) ? 0.0f : 1.0f;
}

extern "C" void kernel_launch(void* const* d_in, const int* in_sizes, int n_in,
                              void* d_out, int out_size, void* d_ws, size_t ws_size,
                              hipStream_t stream) {
  const float* deltas = (const float*)d_in[0];
  const float* locs = (const float*)d_in[1];
  const float* scores = (const float*)d_in[2];
  const int* class_ids = (const int*)d_in[3];
  const int* stride_p = (const int*)d_in[4];

  float* boxes_out = (float*)d_out;                     // n*4 floats
  float* keep_out = (float*)d_out + (size_t)NBOX * 4;   // n floats (0/1)
  float* order_out = (float*)d_out + (size_t)NBOX * 5;  // n floats (indices)

  // workspace layout (all init in-kernel; no memset nodes)
  u32* bmax = (u32*)((char*)d_ws + 64);       // 32*4 B, stored by K1
  int* flag = (int*)((char*)d_ws + 256);      // stored by K2 hazard block
  int* ccpart = (int*)((char*)d_ws + 512);    // 32*80*4 B, stored by K1
  int* rankp = (int*)((char*)d_ws + 16384);   // NS*8192*4 = 1 MiB

  decode_kernel<<<NBLK, 256, 0, stream>>>(
      (const float4*)deltas, (const float2*)locs, stride_p, class_ids,
      (float4*)boxes_out, bmax, ccpart);

  rank_nms_kernel<<<K2GRID, 256, 0, stream>>>(
      scores, class_ids, (const float4*)boxes_out, bmax, ccpart, keep_out,
      flag, rankp);

  scatter_fallback_kernel<<<K3GRID, 256, 0, stream>>>(
      class_ids, (const float4*)boxes_out, bmax, rankp, order_out, keep_out,
      flag);
}